// Round 3
// baseline (218.687 us; speedup 1.0000x reference)
//
#include <hip/hip_runtime.h>
#include <math.h>

#define NHOP 2
#define MEM 32
#define DIM 64

__device__ __forceinline__ float fast_tanh(float x) {
    const float e = __expf(2.f * x);
    return 1.f - 2.f / (e + 1.f);
}

__global__ __launch_bounds__(256, 2) void ripple_fwd(
    const float* __restrict__ hs,     // (B,2,32,64)
    const float* __restrict__ Rs,     // (B,2,32,64,64)
    const float* __restrict__ ts,     // (B,2,32,64)
    const float* __restrict__ vs,     // (B,64)
    const float* __restrict__ W1_w,   // (64,256)
    const float* __restrict__ W1_b,   // (64)
    const float* __restrict__ W2_w,   // (1,64)
    const float* __restrict__ W2_b,   // (1)
    const float* __restrict__ Wmem_w, // (2,64,192)
    const float* __restrict__ Wmem_b, // (2,64)
    const float* __restrict__ z_w,    // (64,128)
    const float* __restrict__ z_b,    // (64)
    float* __restrict__ out)          // (B)
{
    __shared__ float W1T[256][64];        // W1 transposed: W1T[f][d], 64 KB
    __shared__ float Rh_sm[MEM][DIM + 1]; // +1 pad
    __shared__ float M_sm[DIM], o_sm[DIM], onew_sm[DIM], vs_sm[DIM];
    __shared__ float Z_sm[MEM];

    const int b   = blockIdx.x;
    const int tid = threadIdx.x;
    const int l   = tid & 63;
    const int wv  = tid >> 6;

    // ---- W1T staging: lane = d (conflict-free LDS writes: bank = d%32) ----
    {
        const int d  = l;
        const int fq = wv;     // wave-uniform f-block
        #pragma unroll
        for (int j = 0; j < 16; ++j) {
            const int f = fq * 64 + j * 4;
            const float4 w = *reinterpret_cast<const float4*>(W1_w + d * 256 + f);
            W1T[f + 0][d] = w.x;
            W1T[f + 1][d] = w.y;
            W1T[f + 2][d] = w.z;
            W1T[f + 3][d] = w.w;
        }
    }
    if (tid < DIM) {
        const float v = vs[b * DIM + tid];
        M_sm[tid] = v; o_sm[tid] = v; vs_sm[tid] = v;
    }

    const int e0 = l & 3;
    const int dq = l >> 2;

    // ---- Stream hop0: Rh[m][d] = sum_e R[m,d,e] h[m,e]  -> Rh_sm ----
    // Line-exact: every fetched 64B line fully consumed within one instruction.
    {
        const float* __restrict__ Rbase = Rs + (size_t)(b * NHOP) * MEM * DIM * DIM;
        const float* __restrict__ hbase = hs + (size_t)(b * NHOP) * MEM * DIM;
        #pragma unroll 2
        for (int k = 0; k < 8; ++k) {
            const int m = k * 4 + wv;
            const float* __restrict__ Rm = Rbase + (size_t)m * DIM * DIM;
            const float* __restrict__ hm = hbase + m * DIM;
            const float4 hv0 = *reinterpret_cast<const float4*>(hm + 4 * e0);
            const float4 hv1 = *reinterpret_cast<const float4*>(hm + 4 * e0 + 16);
            const float4 hv2 = *reinterpret_cast<const float4*>(hm + 4 * e0 + 32);
            const float4 hv3 = *reinterpret_cast<const float4*>(hm + 4 * e0 + 48);
            #pragma unroll
            for (int dblk = 0; dblk < 4; ++dblk) {
                const int d = dblk * 16 + dq;
                const float* __restrict__ row = Rm + d * DIM + 4 * e0;
                const float4 r0 = *reinterpret_cast<const float4*>(row);
                const float4 r1 = *reinterpret_cast<const float4*>(row + 16);
                const float4 r2 = *reinterpret_cast<const float4*>(row + 32);
                const float4 r3 = *reinterpret_cast<const float4*>(row + 48);
                float p = r0.x*hv0.x + r0.y*hv0.y + r0.z*hv0.z + r0.w*hv0.w;
                p = fmaf(r1.x, hv1.x, fmaf(r1.y, hv1.y, fmaf(r1.z, hv1.z, fmaf(r1.w, hv1.w, p))));
                p = fmaf(r2.x, hv2.x, fmaf(r2.y, hv2.y, fmaf(r2.z, hv2.z, fmaf(r2.w, hv2.w, p))));
                p = fmaf(r3.x, hv3.x, fmaf(r3.y, hv3.y, fmaf(r3.z, hv3.z, fmaf(r3.w, hv3.w, p))));
                p += __shfl_xor(p, 1);
                p += __shfl_xor(p, 2);
                if (e0 == 0) Rh_sm[m][d] = p;
            }
        }
    }
    __syncthreads();   // bar 1: Rh_sm(hop0), W1T, vs ready

    // ---- Stream hop1 -> registers (shfl-reduced); no LDS, no barrier dep ----
    float a1[8][4];
    {
        const float* __restrict__ Rbase = Rs + ((size_t)(b * NHOP) + 1) * MEM * DIM * DIM;
        const float* __restrict__ hbase = hs + ((size_t)(b * NHOP) + 1) * MEM * DIM;
        #pragma unroll
        for (int k = 0; k < 8; ++k) {
            const int m = k * 4 + wv;
            const float* __restrict__ Rm = Rbase + (size_t)m * DIM * DIM;
            const float* __restrict__ hm = hbase + m * DIM;
            const float4 hv0 = *reinterpret_cast<const float4*>(hm + 4 * e0);
            const float4 hv1 = *reinterpret_cast<const float4*>(hm + 4 * e0 + 16);
            const float4 hv2 = *reinterpret_cast<const float4*>(hm + 4 * e0 + 32);
            const float4 hv3 = *reinterpret_cast<const float4*>(hm + 4 * e0 + 48);
            #pragma unroll
            for (int dblk = 0; dblk < 4; ++dblk) {
                const int d = dblk * 16 + dq;
                const float* __restrict__ row = Rm + d * DIM + 4 * e0;
                const float4 r0 = *reinterpret_cast<const float4*>(row);
                const float4 r1 = *reinterpret_cast<const float4*>(row + 16);
                const float4 r2 = *reinterpret_cast<const float4*>(row + 32);
                const float4 r3 = *reinterpret_cast<const float4*>(row + 48);
                float p = r0.x*hv0.x + r0.y*hv0.y + r0.z*hv0.z + r0.w*hv0.w;
                p = fmaf(r1.x, hv1.x, fmaf(r1.y, hv1.y, fmaf(r1.z, hv1.z, fmaf(r1.w, hv1.w, p))));
                p = fmaf(r2.x, hv2.x, fmaf(r2.y, hv2.y, fmaf(r2.z, hv2.z, fmaf(r2.w, hv2.w, p))));
                p = fmaf(r3.x, hv3.x, fmaf(r3.y, hv3.y, fmaf(r3.z, hv3.z, fmaf(r3.w, hv3.w, p))));
                p += __shfl_xor(p, 1);
                p += __shfl_xor(p, 2);
                a1[k][dblk] = p;   // valid in e0==0 lanes
            }
        }
    }

    for (int hop = 0; hop < NHOP; ++hop) {
        const float* __restrict__ tbase = ts + (size_t)(b * NHOP + hop) * MEM * DIM;

        // ---- P2: hcode = tanh(W1 @ z + b1); Z[m] = W2 . hcode + b2 ----
        {
            const int d4 = tid & 15;
            const int mg = tid >> 4;
            float acc0[4] = {0.f, 0.f, 0.f, 0.f};
            float acc1[4] = {0.f, 0.f, 0.f, 0.f};
            #pragma unroll 4
            for (int e = 0; e < 64; ++e) {
                const float4 w0 = *reinterpret_cast<const float4*>(&W1T[e      ][d4 * 4]);
                const float4 w1 = *reinterpret_cast<const float4*>(&W1T[64  + e][d4 * 4]);
                const float4 w2 = *reinterpret_cast<const float4*>(&W1T[128 + e][d4 * 4]);
                const float4 w3 = *reinterpret_cast<const float4*>(&W1T[192 + e][d4 * 4]);
                const float oe  = o_sm[e];
                const float Me  = M_sm[e];
                const float rh0 = Rh_sm[mg][e];
                const float rh1 = Rh_sm[mg + 16][e];
                {
                    const float z0 = rh0 * oe, z1 = rh0 * Me;
                    const float z2 = fabsf(rh0 - oe), z3 = fabsf(rh0 - Me);
                    acc0[0] = fmaf(z0, w0.x, fmaf(z1, w1.x, fmaf(z2, w2.x, fmaf(z3, w3.x, acc0[0]))));
                    acc0[1] = fmaf(z0, w0.y, fmaf(z1, w1.y, fmaf(z2, w2.y, fmaf(z3, w3.y, acc0[1]))));
                    acc0[2] = fmaf(z0, w0.z, fmaf(z1, w1.z, fmaf(z2, w2.z, fmaf(z3, w3.z, acc0[2]))));
                    acc0[3] = fmaf(z0, w0.w, fmaf(z1, w1.w, fmaf(z2, w2.w, fmaf(z3, w3.w, acc0[3]))));
                }
                {
                    const float z0 = rh1 * oe, z1 = rh1 * Me;
                    const float z2 = fabsf(rh1 - oe), z3 = fabsf(rh1 - Me);
                    acc1[0] = fmaf(z0, w0.x, fmaf(z1, w1.x, fmaf(z2, w2.x, fmaf(z3, w3.x, acc1[0]))));
                    acc1[1] = fmaf(z0, w0.y, fmaf(z1, w1.y, fmaf(z2, w2.y, fmaf(z3, w3.y, acc1[1]))));
                    acc1[2] = fmaf(z0, w0.z, fmaf(z1, w1.z, fmaf(z2, w2.z, fmaf(z3, w3.z, acc1[2]))));
                    acc1[3] = fmaf(z0, w0.w, fmaf(z1, w1.w, fmaf(z2, w2.w, fmaf(z3, w3.w, acc1[3]))));
                }
            }
            float p0 = 0.f, p1 = 0.f;
            #pragma unroll
            for (int k2 = 0; k2 < 4; ++k2) {
                const int dd = d4 * 4 + k2;
                const float w2v = W2_w[dd];
                p0 += fast_tanh(acc0[k2] + W1_b[dd]) * w2v;
                p1 += fast_tanh(acc1[k2] + W1_b[dd]) * w2v;
            }
            #pragma unroll
            for (int s = 1; s < 16; s <<= 1) {
                p0 += __shfl_xor(p0, s, 64);
                p1 += __shfl_xor(p1, s, 64);
            }
            if (d4 == 0) {
                Z_sm[mg]      = p0 + W2_b[0];
                Z_sm[mg + 16] = p1 + W2_b[0];
            }
        }
        __syncthreads();   // bar 2/4: Z_sm ready, Rh_sm free

        if (hop == 0) {
            // dump hop1 regs -> Rh_sm (all waves; concurrent with wave0 cluster)
            #pragma unroll
            for (int k = 0; k < 8; ++k) {
                const int m = k * 4 + wv;
                #pragma unroll
                for (int dblk = 0; dblk < 4; ++dblk)
                    if (e0 == 0) Rh_sm[m][dblk * 16 + dq] = a1[k][dblk];
            }
        }

        // ---- wave0 cluster: softmax + o_new + M update (no internal barriers) ----
        if (tid < DIM) {
            float mx = Z_sm[0];
            #pragma unroll
            for (int m = 1; m < MEM; ++m) mx = fmaxf(mx, Z_sm[m]);
            float s = 0.f;
            #pragma unroll
            for (int m = 0; m < MEM; ++m) s += __expf(Z_sm[m] - mx);
            float acc = 0.f;
            #pragma unroll
            for (int m = 0; m < MEM; ++m)
                acc = fmaf(tbase[m * DIM + tid], __expf(Z_sm[m] - mx), acc);
            const float onew = acc / s;
            onew_sm[tid] = onew;   // wave-internal RAW: lockstep + lgkmcnt, no barrier

            const float* __restrict__ Wm = Wmem_w + (size_t)(hop * DIM + tid) * 192;
            float acc2 = Wmem_b[hop * DIM + tid];
            #pragma unroll
            for (int k = 0; k < 16; ++k) {
                const float4 w = *reinterpret_cast<const float4*>(Wm + 4 * k);
                acc2 += w.x * M_sm[4*k] + w.y * M_sm[4*k+1] + w.z * M_sm[4*k+2] + w.w * M_sm[4*k+3];
            }
            #pragma unroll
            for (int k = 0; k < 16; ++k) {
                const float4 w = *reinterpret_cast<const float4*>(Wm + 64 + 4 * k);
                acc2 += w.x * onew_sm[4*k] + w.y * onew_sm[4*k+1] + w.z * onew_sm[4*k+2] + w.w * onew_sm[4*k+3];
            }
            #pragma unroll
            for (int k = 0; k < 16; ++k) {
                const float4 w = *reinterpret_cast<const float4*>(Wm + 128 + 4 * k);
                acc2 += w.x * o_sm[4*k] + w.y * o_sm[4*k+1] + w.z * o_sm[4*k+2] + w.w * o_sm[4*k+3];
            }
            M_sm[tid] = fmaxf(acc2, 0.f);   // reads above precede write: wave lockstep
            o_sm[tid] = onew;
        }
        if (hop == 0) __syncthreads();   // bar 3: Rh_sm(hop1) + M/o visible to all
    }

    // ---- Final (wave0 only; M_sm/o_sm written by wave0 itself) ----
    if (tid < DIM) {
        const float* __restrict__ zr = z_w + (size_t)tid * 128;
        float u = z_b[tid];
        #pragma unroll
        for (int k = 0; k < 16; ++k) {
            const float4 w = *reinterpret_cast<const float4*>(zr + 4 * k);
            u += w.x * M_sm[4*k] + w.y * M_sm[4*k+1] + w.z * M_sm[4*k+2] + w.w * M_sm[4*k+3];
        }
        #pragma unroll
        for (int k = 0; k < 16; ++k) {
            const float4 w = *reinterpret_cast<const float4*>(zr + 64 + 4 * k);
            u += w.x * vs_sm[4*k] + w.y * vs_sm[4*k+1] + w.z * vs_sm[4*k+2] + w.w * vs_sm[4*k+3];
        }
        float r = vs_sm[tid] * u;
        #pragma unroll
        for (int s = 1; s < 64; s <<= 1) r += __shfl_xor(r, s, 64);
        if (tid == 0) out[b] = r;
    }
}

extern "C" void kernel_launch(void* const* d_in, const int* in_sizes, int n_in,
                              void* d_out, int out_size, void* d_ws, size_t ws_size,
                              hipStream_t stream)
{
    const float* hs     = (const float*)d_in[0];
    const float* Rs     = (const float*)d_in[1];
    const float* ts     = (const float*)d_in[2];
    const float* vs     = (const float*)d_in[3];
    const float* W1_w   = (const float*)d_in[4];
    const float* W1_b   = (const float*)d_in[5];
    const float* W2_w   = (const float*)d_in[6];
    const float* W2_b   = (const float*)d_in[7];
    const float* Wmem_w = (const float*)d_in[8];
    const float* Wmem_b = (const float*)d_in[9];
    const float* z_w    = (const float*)d_in[10];
    const float* z_b    = (const float*)d_in[11];
    float* out = (float*)d_out;

    const int B = out_size;  // 1024
    ripple_fwd<<<B, 256, 0, stream>>>(hs, Rs, ts, vs, W1_w, W1_b, W2_w, W2_b,
                                      Wmem_w, Wmem_b, z_w, z_b, out);
}

// Round 4
// 215.505 us; speedup vs baseline: 1.0148x; 1.0148x over previous
//
#include <hip/hip_runtime.h>
#include <math.h>

#define NHOP 2
#define MEM 32
#define DIM 64

typedef __attribute__((ext_vector_type(8))) short short8v;
typedef __attribute__((ext_vector_type(4))) float f32x4;

__device__ __forceinline__ float fast_tanh(float x) {
    const float e = __expf(2.f * x);
    return 1.f - 2.f / (e + 1.f);
}

// round-to-nearest-even fp32 -> bf16 bits
__device__ __forceinline__ short bf16b(float x) {
    union { float f; unsigned u; } c; c.f = x;
    const unsigned r = c.u + 0x7fffu + ((c.u >> 16) & 1u);
    return (short)(r >> 16);
}

__global__ __launch_bounds__(256, 3) void ripple_fwd(
    const float* __restrict__ hs,     // (B,2,32,64)
    const float* __restrict__ Rs,     // (B,2,32,64,64)
    const float* __restrict__ ts,     // (B,2,32,64)
    const float* __restrict__ vs,     // (B,64)
    const float* __restrict__ W1_w,   // (64,256)
    const float* __restrict__ W1_b,   // (64)
    const float* __restrict__ W2_w,   // (1,64)
    const float* __restrict__ W2_b,   // (1)
    const float* __restrict__ Wmem_w, // (2,64,192)
    const float* __restrict__ Wmem_b, // (2,64)
    const float* __restrict__ z_w,    // (64,128)
    const float* __restrict__ z_b,    // (64)
    float* __restrict__ out)          // (B)
{
    // B-fragments of W1T (bf16), frag order: frag = kt*4+nt, 64 lanes x 16B each.
    __shared__ uint4 W1B[32 * 64];                 // 32 KB
    __shared__ float Rh_sm[MEM][68];               // stride 68: 16B-aligned rows, low conflict
    __shared__ float M_sm[DIM], o_sm[DIM], onew_sm[DIM], vs_sm[DIM];
    __shared__ float Zp[2][MEM];
    __shared__ float cvec[128];                    // [0..63]=W1_b, [64..127]=W2_w

    const int b   = blockIdx.x;
    const int tid = threadIdx.x;
    const int l   = tid & 63;
    const int wv  = tid >> 6;

    // ---- One-time: stage W1 as bf16 B-frags. Convention (shared with A-gen):
    // frag (kt,nt): lane ll holds f = kt*32 + (ll>>4)*8 + p, n = nt*16 + (ll&15), p=0..7.
    #pragma unroll
    for (int t = 0; t < 8; ++t) {
        const int s    = t * 256 + tid;
        const int frag = s >> 6, ll = s & 63;
        const int kt = frag >> 2, nt = frag & 3;
        const int n  = nt * 16 + (ll & 15);
        const int f0 = kt * 32 + (ll >> 4) * 8;
        const float4 wa = *reinterpret_cast<const float4*>(W1_w + n * 256 + f0);
        const float4 wb = *reinterpret_cast<const float4*>(W1_w + n * 256 + f0 + 4);
        short8v v;
        v[0] = bf16b(wa.x); v[1] = bf16b(wa.y); v[2] = bf16b(wa.z); v[3] = bf16b(wa.w);
        v[4] = bf16b(wb.x); v[5] = bf16b(wb.y); v[6] = bf16b(wb.z); v[7] = bf16b(wb.w);
        *reinterpret_cast<short8v*>(&W1B[s]) = v;
    }
    if (tid < DIM) {
        cvec[tid]      = W1_b[tid];
        cvec[64 + tid] = W2_w[tid];
        const float v = vs[b * DIM + tid];
        M_sm[tid] = v; o_sm[tid] = v; vs_sm[tid] = v;
    }
    // no barrier needed yet: first consumer of W1B/cvec/M/o is P2, after bar1.

    const int e0s = l & 3;    // stream e-slice
    const int dq  = l >> 2;

    for (int hop = 0; hop < NHOP; ++hop) {
        const float* __restrict__ Rbase = Rs + (size_t)(b * NHOP + hop) * MEM * DIM * DIM;
        const float* __restrict__ hbase = hs + (size_t)(b * NHOP + hop) * MEM * DIM;
        const float* __restrict__ tbase = ts + (size_t)(b * NHOP + hop) * MEM * DIM;

        // ---- Phase 1: stream R -> Rh_sm (line-exact; every 64B line consumed in-instruction)
        #pragma unroll 2
        for (int k = 0; k < 8; ++k) {
            const int m = k * 4 + wv;
            const float* __restrict__ Rm = Rbase + (size_t)m * DIM * DIM;
            const float* __restrict__ hm = hbase + m * DIM;
            const float4 hv0 = *reinterpret_cast<const float4*>(hm + 4 * e0s);
            const float4 hv1 = *reinterpret_cast<const float4*>(hm + 4 * e0s + 16);
            const float4 hv2 = *reinterpret_cast<const float4*>(hm + 4 * e0s + 32);
            const float4 hv3 = *reinterpret_cast<const float4*>(hm + 4 * e0s + 48);
            #pragma unroll
            for (int dblk = 0; dblk < 4; ++dblk) {
                const int d = dblk * 16 + dq;
                const float* __restrict__ row = Rm + d * DIM + 4 * e0s;
                const float4 r0 = *reinterpret_cast<const float4*>(row);
                const float4 r1 = *reinterpret_cast<const float4*>(row + 16);
                const float4 r2 = *reinterpret_cast<const float4*>(row + 32);
                const float4 r3 = *reinterpret_cast<const float4*>(row + 48);
                float p = r0.x*hv0.x + r0.y*hv0.y + r0.z*hv0.z + r0.w*hv0.w;
                p = fmaf(r1.x, hv1.x, fmaf(r1.y, hv1.y, fmaf(r1.z, hv1.z, fmaf(r1.w, hv1.w, p))));
                p = fmaf(r2.x, hv2.x, fmaf(r2.y, hv2.y, fmaf(r2.z, hv2.z, fmaf(r2.w, hv2.w, p))));
                p = fmaf(r3.x, hv3.x, fmaf(r3.y, hv3.y, fmaf(r3.z, hv3.z, fmaf(r3.w, hv3.w, p))));
                p += __shfl_xor(p, 1);
                p += __shfl_xor(p, 2);
                if (e0s == 0) Rh_sm[m][d] = p;
            }
        }
        __syncthreads();   // bar1: Rh_sm ready (+ W1B/cvec/M/o on hop 0)

        // ---- Phase 2 (MFMA): preact = z @ W1T ; Z = W2 . tanh(preact + b1)
        // wave wv: mt = wv&1 (m-tile), nh = wv>>1 (n-half: tiles nh*2, nh*2+1)
        {
            const int g   = l >> 4;
            const int col = l & 15;
            const int mt  = wv & 1;
            const int nh  = wv >> 1;
            const int m   = mt * 16 + col;
            f32x4 acc0 = {0.f, 0.f, 0.f, 0.f};
            f32x4 acc1 = {0.f, 0.f, 0.f, 0.f};
            #pragma unroll
            for (int kt = 0; kt < 8; ++kt) {
                const int part = kt >> 1;              // 0:Rh*o 1:Rh*M 2:|Rh-o| 3:|Rh-M|
                const int e0 = (kt & 1) * 32 + g * 8;  // e-range within DIM
                const float4 r0 = *reinterpret_cast<const float4*>(&Rh_sm[m][e0]);
                const float4 r1 = *reinterpret_cast<const float4*>(&Rh_sm[m][e0 + 4]);
                const float* vsrc = (part & 1) ? M_sm : o_sm;
                const float4 q0 = *reinterpret_cast<const float4*>(vsrc + e0);
                const float4 q1 = *reinterpret_cast<const float4*>(vsrc + e0 + 4);
                float zz[8];
                if (part < 2) {
                    zz[0] = r0.x*q0.x; zz[1] = r0.y*q0.y; zz[2] = r0.z*q0.z; zz[3] = r0.w*q0.w;
                    zz[4] = r1.x*q1.x; zz[5] = r1.y*q1.y; zz[6] = r1.z*q1.z; zz[7] = r1.w*q1.w;
                } else {
                    zz[0] = fabsf(r0.x-q0.x); zz[1] = fabsf(r0.y-q0.y);
                    zz[2] = fabsf(r0.z-q0.z); zz[3] = fabsf(r0.w-q0.w);
                    zz[4] = fabsf(r1.x-q1.x); zz[5] = fabsf(r1.y-q1.y);
                    zz[6] = fabsf(r1.z-q1.z); zz[7] = fabsf(r1.w-q1.w);
                }
                short8v a;
                a[0] = bf16b(zz[0]); a[1] = bf16b(zz[1]); a[2] = bf16b(zz[2]); a[3] = bf16b(zz[3]);
                a[4] = bf16b(zz[4]); a[5] = bf16b(zz[5]); a[6] = bf16b(zz[6]); a[7] = bf16b(zz[7]);
                const short8v b0 = *reinterpret_cast<const short8v*>(&W1B[(kt * 4 + nh * 2 + 0) * 64 + l]);
                const short8v b1 = *reinterpret_cast<const short8v*>(&W1B[(kt * 4 + nh * 2 + 1) * 64 + l]);
                acc0 = __builtin_amdgcn_mfma_f32_16x16x32_bf16(a, b0, acc0, 0, 0, 0);
                acc1 = __builtin_amdgcn_mfma_f32_16x16x32_bf16(a, b1, acc1, 0, 0, 0);
            }
            // Epilogue: D[m'][n] at col=l&15, row=4*g+r (m89-verified). Z-partials.
            const int n0 = (nh * 2 + 0) * 16 + col;
            const int n1 = (nh * 2 + 1) * 16 + col;
            const float b1a = cvec[n0], b1b = cvec[n1];
            const float w2a = cvec[64 + n0], w2b = cvec[64 + n1];
            float pz[4];
            #pragma unroll
            for (int r = 0; r < 4; ++r)
                pz[r] = fast_tanh(acc0[r] + b1a) * w2a + fast_tanh(acc1[r] + b1b) * w2b;
            #pragma unroll
            for (int s = 1; s < 16; s <<= 1) {
                pz[0] += __shfl_xor(pz[0], s, 64);
                pz[1] += __shfl_xor(pz[1], s, 64);
                pz[2] += __shfl_xor(pz[2], s, 64);
                pz[3] += __shfl_xor(pz[3], s, 64);
            }
            if (col == 0) {
                #pragma unroll
                for (int r = 0; r < 4; ++r)
                    Zp[nh][mt * 16 + 4 * g + r] = pz[r];
            }
        }
        __syncthreads();   // bar2: Zp ready; Rh_sm free

        // ---- wave0 cluster: softmax + o_new + M update ----
        if (tid < DIM) {
            float mx = -1e30f;
            #pragma unroll
            for (int m = 0; m < MEM; ++m) mx = fmaxf(mx, Zp[0][m] + Zp[1][m]);
            float s = 0.f, accn = 0.f;
            #pragma unroll
            for (int m = 0; m < MEM; ++m) {
                const float e = __expf(Zp[0][m] + Zp[1][m] - mx);
                s += e;
                accn = fmaf(tbase[m * DIM + tid], e, accn);
            }
            const float onew = accn / s;
            onew_sm[tid] = onew;   // wave-internal RAW: lockstep, no barrier

            const float* __restrict__ Wm = Wmem_w + (size_t)(hop * DIM + tid) * 192;
            float acc2 = Wmem_b[hop * DIM + tid];
            #pragma unroll
            for (int k = 0; k < 16; ++k) {
                const float4 w = *reinterpret_cast<const float4*>(Wm + 4 * k);
                acc2 += w.x * M_sm[4*k] + w.y * M_sm[4*k+1] + w.z * M_sm[4*k+2] + w.w * M_sm[4*k+3];
            }
            #pragma unroll
            for (int k = 0; k < 16; ++k) {
                const float4 w = *reinterpret_cast<const float4*>(Wm + 64 + 4 * k);
                acc2 += w.x * onew_sm[4*k] + w.y * onew_sm[4*k+1] + w.z * onew_sm[4*k+2] + w.w * onew_sm[4*k+3];
            }
            #pragma unroll
            for (int k = 0; k < 16; ++k) {
                const float4 w = *reinterpret_cast<const float4*>(Wm + 128 + 4 * k);
                acc2 += w.x * o_sm[4*k] + w.y * o_sm[4*k+1] + w.z * o_sm[4*k+2] + w.w * o_sm[4*k+3];
            }
            M_sm[tid] = fmaxf(acc2, 0.f);
            o_sm[tid] = onew;
        }
        if (hop == 0) __syncthreads();   // bar3: M/o visible to all waves for hop1 P2
    }

    // ---- Final (wave0 only) ----
    if (tid < DIM) {
        const float* __restrict__ zr = z_w + (size_t)tid * 128;
        float u = z_b[tid];
        #pragma unroll
        for (int k = 0; k < 16; ++k) {
            const float4 w = *reinterpret_cast<const float4*>(zr + 4 * k);
            u += w.x * M_sm[4*k] + w.y * M_sm[4*k+1] + w.z * M_sm[4*k+2] + w.w * M_sm[4*k+3];
        }
        #pragma unroll
        for (int k = 0; k < 16; ++k) {
            const float4 w = *reinterpret_cast<const float4*>(zr + 64 + 4 * k);
            u += w.x * vs_sm[4*k] + w.y * vs_sm[4*k+1] + w.z * vs_sm[4*k+2] + w.w * vs_sm[4*k+3];
        }
        float r = vs_sm[tid] * u;
        #pragma unroll
        for (int s = 1; s < 64; s <<= 1) r += __shfl_xor(r, s, 64);
        if (tid == 0) out[b] = r;
    }
}

extern "C" void kernel_launch(void* const* d_in, const int* in_sizes, int n_in,
                              void* d_out, int out_size, void* d_ws, size_t ws_size,
                              hipStream_t stream)
{
    const float* hs     = (const float*)d_in[0];
    const float* Rs     = (const float*)d_in[1];
    const float* ts     = (const float*)d_in[2];
    const float* vs     = (const float*)d_in[3];
    const float* W1_w   = (const float*)d_in[4];
    const float* W1_b   = (const float*)d_in[5];
    const float* W2_w   = (const float*)d_in[6];
    const float* W2_b   = (const float*)d_in[7];
    const float* Wmem_w = (const float*)d_in[8];
    const float* Wmem_b = (const float*)d_in[9];
    const float* z_w    = (const float*)d_in[10];
    const float* z_b    = (const float*)d_in[11];
    float* out = (float*)d_out;

    const int B = out_size;  // 1024
    ripple_fwd<<<B, 256, 0, stream>>>(hs, Rs, ts, vs, W1_w, W1_b, W2_w, W2_b,
                                      Wmem_w, Wmem_b, z_w, z_b, out);
}